// Round 9
// baseline (27.345 us; speedup 1.0000x reference)
//
#include <hip/hip_runtime.h>
#include <math.h>

#define L_SEQ 4096   // sequence length L
#define NT 512       // threads per block (one block per sequence)
#define CHUNK 8      // elements per thread
#define NW (NT/64)   // waves per block (8)

struct M2 { float a00, a01, a10, a11; };

// max-plus 2x2 compose: C[s][t] = max_k(A[s][k] + B[k][t])
__device__ __forceinline__ M2 mpc(const M2& A, const M2& B) {
  M2 C;
  C.a00 = fmaxf(A.a00 + B.a00, A.a01 + B.a10);
  C.a01 = fmaxf(A.a00 + B.a01, A.a01 + B.a11);
  C.a10 = fmaxf(A.a10 + B.a00, A.a11 + B.a10);
  C.a11 = fmaxf(A.a10 + B.a01, A.a11 + B.a11);
  return C;
}

__device__ __forceinline__ M2 ldm(const float4& v) { return M2{v.x, v.y, v.z, v.w}; }
__device__ __forceinline__ float4 stm(const M2& m) { return make_float4(m.a00, m.a01, m.a10, m.a11); }

typedef float f4v __attribute__((ext_vector_type(4)));
__device__ __forceinline__ void nt_store4(float* p, float a, float b, float c, float d) {
  f4v v = {a, b, c, d};
  __builtin_nontemporal_store(v, (f4v*)p);
}

// DPP cross-lane fetch (VALU pipe, no LDS traffic). ctrl: 0x110+N = row_shr:N,
// 0x142 = row_bcast:15 (lane15->lanes16-31, lane31->32-47, lane47->48-63),
// 0x143 = row_bcast:31 (lane31 -> lanes 32-63).
template <int CTRL>
__device__ __forceinline__ float dppf(float x) {
  return __int_as_float(__builtin_amdgcn_update_dpp(
      0, __float_as_int(x), CTRL, 0xf, 0xf, true));
}
template <int CTRL>
__device__ __forceinline__ M2 dpp_fetch(const M2& x) {
  M2 r;
  r.a00 = dppf<CTRL>(x.a00); r.a01 = dppf<CTRL>(x.a01);
  r.a10 = dppf<CTRL>(x.a10); r.a11 = dppf<CTRL>(x.a11);
  return r;
}

__global__ __launch_bounds__(NT, 8) void chain_fb_kernel(
    const float* __restrict__ jp, const float* __restrict__ bp,
    const int* __restrict__ obs, float* __restrict__ out) {
  __shared__ float4 T4s[16];                                // 4-bit-pattern transforms
  __shared__ float T8a[256], T8b[256], T8c[256], T8d[256];  // 8-bit LUT, SoA (4 KB)
  __shared__ float4 wtf[NW];   // forward wave totals
  __shared__ float4 wtb[NW];   // backward wave totals

  const int t = threadIdx.x;
  const int lane = t & 63;
  const int w = t >> 6;
  const long b = blockIdx.x;

  const float P   = 0.25f * jp[0];   // psi = [[P,-P],[-P,P]]
  const float hb0 = 0.5f * bp[0];    // u_i = 0.5*b[obs_i]; phi_i = (-u, +u)
  const float hb1 = 0.5f * bp[1];

  // ---- issue obs loads first (latency hidden under LUT build)
  const int4* rowp = (const int4*)(obs + b * L_SEQ + (long)t * CHUNK);
  int4 q0 = rowp[0], q1 = rowp[1];

  // ---- build LUT: pattern p -> E(p0)(*)E(p1)(*)... (bit 0 = earliest elem)
  //      E(u) = [[P-u, -u-P],[u-P, u+P]]
  if (t < 16) {
    float u0 = (t & 1) ? hb1 : hb0;
    M2 Tt{P - u0, -u0 - P, u0 - P, u0 + P};
    #pragma unroll
    for (int k = 1; k < 4; ++k) {
      float uk = ((t >> k) & 1) ? hb1 : hb0;
      M2 Ek{P - uk, -uk - P, uk - P, uk + P};
      Tt = mpc(Tt, Ek);
    }
    T4s[t] = stm(Tt);
  }
  __syncthreads();
  if (t < 256) {  // T8[p] = T4[p&15] (*) T4[p>>4]
    M2 M = mpc(ldm(T4s[t & 15]), ldm(T4s[(t >> 4) & 15]));
    T8a[t] = M.a00; T8b[t] = M.a01; T8c[t] = M.a10; T8d[t] = M.a11;
  }
  // pack obs bit mask while the barrier drains
  const unsigned m =
      (unsigned)(q0.x & 1)       | (unsigned)(q0.y & 1) << 1 |
      (unsigned)(q0.z & 1) << 2  | (unsigned)(q0.w & 1) << 3 |
      (unsigned)(q1.x & 1) << 4  | (unsigned)(q1.y & 1) << 5 |
      (unsigned)(q1.z & 1) << 6  | (unsigned)(q1.w & 1) << 7;
  __syncthreads();

  // ---- chunk transforms.
  // Fwd: this thread's chunk. Bwd (v-space): v-lane l handles chunk 63-l of
  // this wave, so the suffix scan becomes a SECOND forward scan.
  const unsigned mrev = (unsigned)__shfl((int)m, 63 - lane);   // mirrored chunk's mask
  const unsigned r = __brev(mrev) >> 24;                       // its bwd-order pattern
  M2 T {T8a[m], T8b[m], T8c[m], T8d[m]};   // fwd: E(u0)(*)...(*)E(u7)
  M2 Rv{T8a[r], T8b[r], T8c[r], T8d[r]};   // bwd of chunk 63-lane

  // ---- dual Hillis-Steele inclusive scans, cross-lane via DPP (VALU pipe)
  {
    M2 f, g;
    f = dpp_fetch<0x111>(T); g = dpp_fetch<0x111>(Rv);           // row_shr:1
    if ((lane & 15) >= 1) { T = mpc(f, T); Rv = mpc(g, Rv); }
    f = dpp_fetch<0x112>(T); g = dpp_fetch<0x112>(Rv);           // row_shr:2
    if ((lane & 15) >= 2) { T = mpc(f, T); Rv = mpc(g, Rv); }
    f = dpp_fetch<0x114>(T); g = dpp_fetch<0x114>(Rv);           // row_shr:4
    if ((lane & 15) >= 4) { T = mpc(f, T); Rv = mpc(g, Rv); }
    f = dpp_fetch<0x118>(T); g = dpp_fetch<0x118>(Rv);           // row_shr:8
    if ((lane & 15) >= 8) { T = mpc(f, T); Rv = mpc(g, Rv); }
    f = dpp_fetch<0x142>(T); g = dpp_fetch<0x142>(Rv);           // row_bcast:15
    if (lane & 16)        { T = mpc(f, T); Rv = mpc(g, Rv); }    // rows 1,3
    f = dpp_fetch<0x143>(T); g = dpp_fetch<0x143>(Rv);           // row_bcast:31
    if (lane >= 32)       { T = mpc(f, T); Rv = mpc(g, Rv); }    // rows 2,3
  }
  if (lane == 63) { wtf[w] = stm(T); wtb[w] = stm(Rv); }  // full wave totals

  // intra-wave exclusive versions (shift by 1; identity at lane 0)
  M2 EF{__shfl_up(T.a00, 1), __shfl_up(T.a01, 1),
        __shfl_up(T.a10, 1), __shfl_up(T.a11, 1)};
  M2 EB{__shfl_up(Rv.a00, 1), __shfl_up(Rv.a01, 1),
        __shfl_up(Rv.a10, 1), __shfl_up(Rv.a11, 1)};
  if (lane == 0) {
    EF.a00 = 0.f; EF.a01 = -INFINITY; EF.a10 = -INFINITY; EF.a11 = 0.f;
    EB.a00 = 0.f; EB.a01 = -INFINITY; EB.a10 = -INFINITY; EB.a11 = 0.f;
  }

  __syncthreads();  // wave totals visible

  // cross-wave exclusive composition (earlier waves left for fwd; later waves
  // left for bwd — wtb[ww] is already the wave's total in bwd order)
  M2 GF = EF, GB = EB;
  for (int ww = w - 1; ww >= 0; --ww) GF = mpc(ldm(wtf[ww]), GF);
  for (int ww = w + 1; ww < NW; ++ww) GB = mpc(ldm(wtb[ww]), GB);
  // apply zero init vector: msg[t] = max_s G[s][t]
  float fm0 = fmaxf(GF.a00, GF.a10), fm1 = fmaxf(GF.a01, GF.a11);
  const float bv0 = fmaxf(GB.a00, GB.a10), bv1 = fmaxf(GB.a01, GB.a11);
  // bwd message computed at v-lane (63-lane): swap back (2 bpermutes)
  float bm0 = __shfl(bv0, 63 - lane);
  float bm1 = __shfl(bv1, 63 - lane);

  // ---- fwd replay: o = phi + fwd  (x,y are exactly phi+msg)
  float o0[CHUNK], o1[CHUNK];
  #pragma unroll
  for (int e = 0; e < CHUNK; ++e) {
    float u = ((m >> e) & 1) ? hb1 : hb0;
    float x = fm0 - u, y = fm1 + u;
    o0[e] = x; o1[e] = y;
    fm0 = fmaxf(x + P, y - P);
    fm1 = fmaxf(x - P, y + P);
  }
  // ---- bwd replay: add bwd message (right->left)
  #pragma unroll
  for (int e = CHUNK - 1; e >= 0; --e) {
    float u = ((m >> e) & 1) ? hb1 : hb0;
    o0[e] += bm0; o1[e] += bm1;
    float x = bm0 - u, y = bm1 + u;
    bm0 = fmaxf(x + P, y - P);
    bm1 = fmaxf(x - P, y + P);
  }

  // ---- store: contiguous 8 floats per state row, NONTEMPORAL (write-once
  //      data; bypass L2/L3 so obs stays L3-resident across graph replays)
  const long base = (long)t * CHUNK;
  float* r0 = out + b * (2L * L_SEQ) + base;   // out[b][0][base..]
  float* r1 = r0 + L_SEQ;                      // out[b][1][base..]
  nt_store4(r0,     o0[0], o0[1], o0[2], o0[3]);
  nt_store4(r0 + 4, o0[4], o0[5], o0[6], o0[7]);
  nt_store4(r1,     o1[0], o1[1], o1[2], o1[3]);
  nt_store4(r1 + 4, o1[4], o1[5], o1[6], o1[7]);
}

extern "C" void kernel_launch(void* const* d_in, const int* in_sizes, int n_in,
                              void* d_out, int out_size, void* d_ws, size_t ws_size,
                              hipStream_t stream) {
  const float* jp  = (const float*)d_in[0];
  const float* bp  = (const float*)d_in[1];
  const int*   obs = (const int*)d_in[2];
  float* out = (float*)d_out;
  const int B = in_sizes[2] / L_SEQ;   // 2048
  chain_fb_kernel<<<B, NT, 0, stream>>>(jp, bp, obs, out);
}